// Round 5
// baseline (82.251 us; speedup 1.0000x reference)
//
#include <hip/hip_runtime.h>
#include <math.h>

#define D_MODEL   2048
#define N_EXPERTS 64
#define TOP_K     8
#define N_TOKENS  16384
#define TOK_TILE  64
#define NTHREADS  512
#define NCHUNK    32               // 64 floats of K per chunk
// ws layout: [kstep 0..63][nfrag 0..3][ver 0..2][lane 0..63][4 dwords]
#define WS_NEED   (64*4*3*64*16)   // 786432 bytes

typedef __attribute__((ext_vector_type(8))) short bf16x8;
typedef __attribute__((ext_vector_type(4))) float f32x4;
typedef __attribute__((ext_vector_type(4))) int   i32x4;

union FragU { i32x4 i; bf16x8 h; };

// exact 3-way truncation split: x == h+m+l + eps, |eps| <= 2^-24 |x|
__device__ __forceinline__ void split3(float x, unsigned &h, unsigned &m, unsigned &l) {
    unsigned ux = __float_as_uint(x);
    h = ux & 0xffff0000u;
    float mf = x - __uint_as_float(h);       // exact (Sterbenz)
    unsigned um = __float_as_uint(mf) & 0xffff0000u;
    float lf = mf - __uint_as_float(um);     // exact
    m = um;
    l = __float_as_uint(lf) & 0xffff0000u;
}

// async global->LDS 16B copy: per-lane GLOBAL address, wave-uniform LDS base
// (HW writes lane i at lds + 16*i). Swizzle lives on the global side (m173).
__device__ __forceinline__ void async_cp16(const float* g, float* l) {
    __builtin_amdgcn_global_load_lds(
        (const __attribute__((address_space(1))) void*)g,
        (__attribute__((address_space(3))) void*)l, 16, 0, 0);
}

// ---- unchanged from R2 (HW-proven numerics + layout) ----
__global__ __launch_bounds__(256) void pack_w_kernel(const float* __restrict__ gw,
                                                     unsigned* __restrict__ wp) {
    const int g    = blockIdx.x * 256 + threadIdx.x;   // 0..196607
    const int d    = g & 3;
    const int lane = (g >> 2) & 63;
    const int rest = g >> 8;                           // 0..767
    const int v    = rest % 3;
    const int t    = rest / 3;                         // ks*4 + fr
    const int fr   = t & 3;
    const int ks   = t >> 2;
    const int e    = fr * 16 + (lane & 15);            // B col = lane&15
    const int k    = ks * 32 + (lane >> 4) * 8 + 2 * d;
    const float w0 = gw[(size_t)e * D_MODEL + k];
    const float w1 = gw[(size_t)e * D_MODEL + k + 1];
    unsigned h0, m0, l0, h1, m1, l1;
    split3(w0, h0, m0, l0);
    split3(w1, h1, m1, l1);
    const unsigned c0 = (v == 0) ? h0 : ((v == 1) ? m0 : l0);
    const unsigned c1 = (v == 0) ? h1 : ((v == 1) ? m1 : l1);
    wp[g] = (c0 >> 16) | c1;                           // low short = elem0
}

__device__ __forceinline__ void splitpack(const float4 a, const float4 b,
                                          FragU &ph, FragU &pm, FragU &pl) {
    const float f[8] = {a.x, a.y, a.z, a.w, b.x, b.y, b.z, b.w};
#pragma unroll
    for (int d = 0; d < 4; ++d) {
        unsigned h0, m0, l0, h1, m1, l1;
        split3(f[2 * d],     h0, m0, l0);
        split3(f[2 * d + 1], h1, m1, l1);
        ph.i[d] = (int)((h0 >> 16) | h1);
        pm.i[d] = (int)((m0 >> 16) | m1);
        pl.i[d] = (int)((l0 >> 16) | l1);
    }
}

#define MFMA(A_, B_, C_) C_ = __builtin_amdgcn_mfma_f32_16x16x32_bf16((A_).h, (B_).h, C_, 0, 0, 0)

__global__ __launch_bounds__(NTHREADS, 2) void router_mfma(
    const float* __restrict__ x, const unsigned* __restrict__ wp,
    float* __restrict__ out)
{
    // Triple-buffered x tile: written linearly by global_load_lds (no write
    // conflicts); content is slot-swizzled via the GLOBAL source address:
    //   LDS[row][16B-slot s] = x[row][4*(s ^ (row&7))]
    // Readers use s = s_logical ^ (row&7): both parities -> all 32 banks.
    __shared__ __align__(16) float xs[3][TOK_TILE][64];
    __shared__ float lt[TOK_TILE][N_EXPERTS + 1];
    __shared__ float smax[TOK_TILE], srs[TOK_TILE];

    const int tid  = threadIdx.x;
    const int lane = tid & 63;
    const int wv   = tid >> 6;          // 0..7
    const int mrow = wv & 3;            // token quarter (16 rows)
    const int ncol = wv >> 2;           // expert half (32 cols)
    const int m0   = blockIdx.x * TOK_TILE;

    const int lrow = lane & 15;         // A row / B col / C col
    const int lk   = lane >> 4;         // k-group 0..3

    float* xsflat = &xs[0][0][0];
    const int LBUF = TOK_TILE * 64;     // floats per buffer

    // ---- staging coords (2 async-cp16 per wave per chunk) ----
    const int r0  = wv * 8 + (lane >> 4);        // rows wv*8 .. +3
    const int r1  = r0 + 4;                      // rows wv*8+4 .. +7
    const float* src0 = x + (size_t)(m0 + r0) * D_MODEL + 4 * ((lane & 15) ^ (r0 & 7));
    const float* src1 = x + (size_t)(m0 + r1) * D_MODEL + 4 * ((lane & 15) ^ (r1 & 7));
    float* ldst = xsflat + wv * 512;             // + buf*LBUF; i=1 at +256

    // ---- A-fragment read offsets (floats, rel. to buffer base) ----
    const int arow = mrow * 16 + lrow;
    const int am   = lrow & 7;                   // arow&7
    const int offa0 = arow * 64 + 4 * (( 0 + 2 * lk)     ^ am);
    const int offb0 = arow * 64 + 4 * (( 0 + 2 * lk + 1) ^ am);
    const int offa1 = arow * 64 + 4 * (( 8 + 2 * lk)     ^ am);
    const int offb1 = arow * 64 + 4 * (( 8 + 2 * lk + 1) ^ am);

    const unsigned* wb = wp + (size_t)(ncol * 6) * 256 + lane * 4;

    f32x4 acc0a = {0.f, 0.f, 0.f, 0.f};
    f32x4 acc0b = acc0a, acc1a = acc0a, acc1b = acc0a;

    i32x4 BA[12], BB[12];

    // issue-order discipline: x (oldest, HBM) before B (L1/L2) each step, so
    // waits for B never add latency beyond what x already requires, and the
    // compiler's vmcnt(0)-drain at each barrier gives every load >=1 chunk
    // of cover.
#define STAGE_X(cN)                                                          \
    if ((cN) < NCHUNK) {                                                     \
        float* d_ = ldst + ((cN) % 3) * LBUF;                                \
        async_cp16(src0 + (cN) * 64, d_);                                    \
        async_cp16(src1 + (cN) * 64, d_ + 256);                              \
    }

#define LOAD_B(cN, Barr)                                                     \
    if ((cN) < NCHUNK) {                                                     \
        const unsigned* bt0_ = wb + (size_t)(2 * (cN)) * 3072;               \
        const unsigned* bt1_ = bt0_ + 3072;                                  \
        Barr[0]  = *(const i32x4*)(bt0_ +    0);                             \
        Barr[1]  = *(const i32x4*)(bt0_ +  256);                             \
        Barr[2]  = *(const i32x4*)(bt0_ +  512);                             \
        Barr[3]  = *(const i32x4*)(bt0_ +  768);                             \
        Barr[4]  = *(const i32x4*)(bt0_ + 1024);                             \
        Barr[5]  = *(const i32x4*)(bt0_ + 1280);                             \
        Barr[6]  = *(const i32x4*)(bt1_ +    0);                             \
        Barr[7]  = *(const i32x4*)(bt1_ +  256);                             \
        Barr[8]  = *(const i32x4*)(bt1_ +  512);                             \
        Barr[9]  = *(const i32x4*)(bt1_ +  768);                             \
        Barr[10] = *(const i32x4*)(bt1_ + 1024);                             \
        Barr[11] = *(const i32x4*)(bt1_ + 1280);                             \
    }

#define COMPUTE(cN, Barr)                                                    \
    {                                                                        \
        const float* xb_ = xsflat + ((cN) % 3) * LBUF;                       \
        _Pragma("unroll")                                                    \
        for (int j = 0; j < 2; ++j) {                                        \
            const float4 Aa = *(const float4*)(xb_ + (j ? offa1 : offa0));   \
            const float4 Ab = *(const float4*)(xb_ + (j ? offb1 : offb0));   \
            FragU ah, am_, al;                                               \
            splitpack(Aa, Ab, ah, am_, al);                                  \
            FragU b0h, b0m, b0l, b1h, b1m, b1l;                              \
            b0h.i = Barr[j*6+0]; b0m.i = Barr[j*6+1]; b0l.i = Barr[j*6+2];   \
            b1h.i = Barr[j*6+3]; b1m.i = Barr[j*6+4]; b1l.i = Barr[j*6+5];   \
            MFMA(ah, b0h, acc0a); MFMA(am_, b0h, acc0a); MFMA(al, b0h, acc0a);\
            MFMA(ah, b0m, acc0b); MFMA(am_, b0m, acc0b); MFMA(ah, b0l, acc0b);\
            MFMA(ah, b1h, acc1a); MFMA(am_, b1h, acc1a); MFMA(al, b1h, acc1a);\
            MFMA(ah, b1m, acc1b); MFMA(am_, b1m, acc1b); MFMA(ah, b1l, acc1b);\
        }                                                                    \
    }

    // prologue: x[0], x[1] in flight + B[0]; barrier drains all.
    STAGE_X(0);
    STAGE_X(1);
    LOAD_B(0, BA);
    __syncthreads();

#pragma unroll 2
    for (int c = 0; c < NCHUNK; ++c) {
        if (c & 1) {
            STAGE_X(c + 2);
            LOAD_B(c + 1, BA);
            COMPUTE(c, BB);
        } else {
            STAGE_X(c + 2);
            LOAD_B(c + 1, BB);
            COMPUTE(c, BA);
        }
        __syncthreads();
    }

#undef STAGE_X
#undef LOAD_B
#undef COMPUTE

    // ---- C scatter. Layout (m89/R2-verified): col=lane&15, row=(lane>>4)*4+reg
#pragma unroll
    for (int r = 0; r < 4; ++r) {
        lt[mrow * 16 + lk * 4 + r][ncol * 32 +  0 + lrow] = acc0a[r] + acc0b[r];
        lt[mrow * 16 + lk * 4 + r][ncol * 32 + 16 + lrow] = acc1a[r] + acc1b[r];
    }
    __syncthreads();

    // ---- epilogue: identical to the R0/R2-proven path ----
    float* out_idx = out;
    float* out_w   = out + (size_t)N_TOKENS * TOP_K;
    float* out_p   = out + (size_t)2 * N_TOKENS * TOP_K;
    float* out_l   = out_p + (size_t)N_TOKENS * N_EXPERTS;

    if (tid < TOK_TILE) {
        const int t = tid;
        float tv[TOP_K];
        int   ti[TOP_K];
#pragma unroll
        for (int i = 0; i < TOP_K; ++i) { tv[i] = -INFINITY; ti[i] = 0; }
        float m = -INFINITY;

        for (int e = 0; e < N_EXPERTS; ++e) {
            const float v = lt[t][e];
            m = fmaxf(m, v);
            if (v > tv[TOP_K - 1]) {
#pragma unroll
                for (int j = TOP_K - 1; j >= 1; --j) {
                    const bool shift = (v > tv[j - 1]);
                    const bool here  = (v > tv[j]);
                    const float ntv = shift ? tv[j - 1] : (here ? v : tv[j]);
                    const int   nti = shift ? ti[j - 1] : (here ? e : ti[j]);
                    tv[j] = ntv; ti[j] = nti;
                }
                if (v > tv[0]) { tv[0] = v; ti[0] = e; }
            }
        }

        float s = 0.f;
        for (int e = 0; e < N_EXPERTS; ++e) s += expf(lt[t][e] - m);
        const float rs = 1.f / s;
        smax[t] = m;
        srs[t]  = rs;

        float ex[TOP_K];
        float wsum = 0.f;
#pragma unroll
        for (int i = 0; i < TOP_K; ++i) { ex[i] = expf(tv[i] - tv[0]); wsum += ex[i]; }
        const float rw = 1.f / wsum;

        const int tok = m0 + t;
#pragma unroll
        for (int i = 0; i < TOP_K; ++i) {
            out_idx[(size_t)tok * TOP_K + i] = (float)ti[i];
            out_w  [(size_t)tok * TOP_K + i] = ex[i] * rw;
        }
    }
    __syncthreads();

#pragma unroll
    for (int rep = 0; rep < 2; ++rep) {
        const int f = rep * (NTHREADS * 4) + tid * 4;
        const int t = f >> 6;
        const int e = f & 63;
        const float l0 = lt[t][e + 0];
        const float l1 = lt[t][e + 1];
        const float l2 = lt[t][e + 2];
        const float l3 = lt[t][e + 3];
        const float mm = smax[t];
        const float rr = srs[t];
        float4 pv = make_float4(expf(l0 - mm) * rr, expf(l1 - mm) * rr,
                                expf(l2 - mm) * rr, expf(l3 - mm) * rr);
        float4 lv = make_float4(l0, l1, l2, l3);
        const size_t gbase = (size_t)m0 * N_EXPERTS + f;
        *(float4*)(out_p + gbase) = pv;
        *(float4*)(out_l + gbase) = lv;
    }
}

// ---------------- fallback (R0-proven fp32 path) if ws too small ----------------
__global__ __launch_bounds__(NTHREADS) void router_fallback(
    const float* __restrict__ x, const float* __restrict__ gw,
    float* __restrict__ out)
{
    __shared__ float xs[TOK_TILE][33];
    __shared__ float wsh[N_EXPERTS][36];
    __shared__ float lt[TOK_TILE][N_EXPERTS + 1];
    __shared__ float smax[TOK_TILE], srs[TOK_TILE];

    const int tid  = threadIdx.x;
    const int lane = tid & 63;
    const int wv   = tid >> 6;
    const int m0   = blockIdx.x * TOK_TILE;
    const int srow = tid >> 3;
    const int skq  = (tid & 7) * 4;

    const float* xsrc = x  + (size_t)(m0 + srow) * D_MODEL + skq;
    const float* wsrc = gw + (size_t)srow        * D_MODEL + skq;
    float4 xr = *(const float4*)(xsrc);
    float4 wr = *(const float4*)(wsrc);

    float acc[8];
#pragma unroll
    for (int i = 0; i < 8; ++i) acc[i] = 0.f;
    const int e0 = wv * 8;

    for (int c = 0; c < D_MODEL / 32; ++c) {
        xs[srow][skq] = xr.x; xs[srow][skq+1] = xr.y; xs[srow][skq+2] = xr.z; xs[srow][skq+3] = xr.w;
        *(float4*)&wsh[srow][skq] = wr;
        __syncthreads();
        if (c + 1 < D_MODEL / 32) {
            xr = *(const float4*)(xsrc + (c + 1) * 32);
            wr = *(const float4*)(wsrc + (c + 1) * 32);
        }
#pragma unroll 8
        for (int k4 = 0; k4 < 8; ++k4) {
            const float4 xv = *(const float4*)&xs[lane][k4 * 4];
#pragma unroll
            for (int e = 0; e < 8; ++e) {
                const float4 w4 = *(const float4*)&wsh[e0 + e][k4 * 4];
                acc[e] = fmaf(xv.x, w4.x, fmaf(xv.y, w4.y, fmaf(xv.z, w4.z, fmaf(xv.w, w4.w, acc[e]))));
            }
        }
        __syncthreads();
    }
#pragma unroll
    for (int e = 0; e < 8; ++e) lt[lane][e0 + e] = acc[e];
    __syncthreads();

    float* out_idx = out;
    float* out_w   = out + (size_t)N_TOKENS * TOP_K;
    float* out_p   = out + (size_t)2 * N_TOKENS * TOP_K;
    float* out_l   = out_p + (size_t)N_TOKENS * N_EXPERTS;

    if (tid < TOK_TILE) {
        const int t = tid;
        float tv[TOP_K]; int ti[TOP_K];
#pragma unroll
        for (int i = 0; i < TOP_K; ++i) { tv[i] = -INFINITY; ti[i] = 0; }
        float m = -INFINITY;
        for (int e = 0; e < N_EXPERTS; ++e) {
            const float v = lt[t][e];
            m = fmaxf(m, v);
            if (v > tv[TOP_K - 1]) {
#pragma unroll
                for (int j = TOP_K - 1; j >= 1; --j) {
                    const bool shift = (v > tv[j - 1]);
                    const bool here  = (v > tv[j]);
                    const float ntv = shift ? tv[j - 1] : (here ? v : tv[j]);
                    const int   nti = shift ? ti[j - 1] : (here ? e : ti[j]);
                    tv[j] = ntv; ti[j] = nti;
                }
                if (v > tv[0]) { tv[0] = v; ti[0] = e; }
            }
        }
        float s = 0.f;
        for (int e = 0; e < N_EXPERTS; ++e) s += expf(lt[t][e] - m);
        const float rs = 1.f / s;
        smax[t] = m; srs[t] = rs;
        float ex[TOP_K]; float wsum = 0.f;
#pragma unroll
        for (int i = 0; i < TOP_K; ++i) { ex[i] = expf(tv[i] - tv[0]); wsum += ex[i]; }
        const float rw = 1.f / wsum;
        const int tok = m0 + t;
#pragma unroll
        for (int i = 0; i < TOP_K; ++i) {
            out_idx[(size_t)tok * TOP_K + i] = (float)ti[i];
            out_w  [(size_t)tok * TOP_K + i] = ex[i] * rw;
        }
    }
    __syncthreads();
#pragma unroll
    for (int rep = 0; rep < 2; ++rep) {
        const int f = rep * (NTHREADS * 4) + tid * 4;
        const int t = f >> 6;
        const int e = f & 63;
        const float l0 = lt[t][e], l1 = lt[t][e+1], l2 = lt[t][e+2], l3 = lt[t][e+3];
        const float mm = smax[t], rr = srs[t];
        float4 pv = make_float4(expf(l0-mm)*rr, expf(l1-mm)*rr, expf(l2-mm)*rr, expf(l3-mm)*rr);
        float4 lv = make_float4(l0, l1, l2, l3);
        const size_t gbase = (size_t)m0 * N_EXPERTS + f;
        *(float4*)(out_p + gbase) = pv;
        *(float4*)(out_l + gbase) = lv;
    }
}

extern "C" void kernel_launch(void* const* d_in, const int* in_sizes, int n_in,
                              void* d_out, int out_size, void* d_ws, size_t ws_size,
                              hipStream_t stream) {
    const float* x  = (const float*)d_in[0];
    const float* gw = (const float*)d_in[1];
    float* out = (float*)d_out;
    if (ws_size >= (size_t)WS_NEED) {
        unsigned* wp = (unsigned*)d_ws;
        pack_w_kernel<<<dim3(WS_NEED / 4 / 256), dim3(256), 0, stream>>>(gw, wp);
        router_mfma<<<dim3(N_TOKENS / TOK_TILE), dim3(NTHREADS), 0, stream>>>(x, wp, out);
    } else {
        router_fallback<<<dim3(N_TOKENS / TOK_TILE), dim3(NTHREADS), 0, stream>>>(x, gw, out);
    }
}